// Round 1
// baseline (1183.609 us; speedup 1.0000x reference)
//
#include <hip/hip_runtime.h>
#include <hip/hip_bf16.h>

#define B_ 16
#define T_ 2048
#define J_ 128
#define D_ 1024
#define TT 64
#define KC 32

// ws layout (floats): uwb[B*J] @0, agg2[B*D] @2048  (~74 KB total)
#define WS_UWB  0
#define WS_AGG2 2048

// out layout (floats)
#define OFF_ATT1 0
#define OFF_ATT2 4194304UL
#define OFF_G    4227072UL

typedef float4 f4;

// ---------------- K1: uwb[b,j] = U[b,j,:].w2 + bias ----------------
__global__ __launch_bounds__(256) void k_uwb(const float* __restrict__ U,
                                             const float* __restrict__ w,
                                             const float* __restrict__ bias,
                                             float* __restrict__ ws) {
    int bj = blockIdx.x;
    const float* Urow = U + (size_t)bj * D_;
    const float* w2 = w + D_;
    float s = 0.f;
    for (int i = threadIdx.x; i < D_; i += 256) s = fmaf(Urow[i], w2[i], s);
#pragma unroll
    for (int off = 32; off > 0; off >>= 1) s += __shfl_down(s, off, 64);
    __shared__ float red[4];
    if ((threadIdx.x & 63) == 0) red[threadIdx.x >> 6] = s;
    __syncthreads();
    if (threadIdx.x == 0)
        ws[WS_UWB + bj] = red[0] + red[1] + red[2] + red[3] + bias[0];
}

// ---------------- K2: scores -> softmax -> att1, m, agg1, G chunks 0..2 ----
struct SMemK2 {
    union {
        struct { float Ht[TT][36]; float Ut[J_][36]; float w1s[KC]; } g1;
        float P[TT][132];
    } u;
    float uwbs[J_];
};

__global__ __launch_bounds__(256) void k_main(const float* __restrict__ H,
                                              const float* __restrict__ U,
                                              const float* __restrict__ w,
                                              const float* __restrict__ ws,
                                              float* __restrict__ out) {
    __shared__ SMemK2 sm;
    const int tid = threadIdx.x;
    const int tx = tid & 15, ty = tid >> 4;
    const int b = blockIdx.y;
    const int t0 = blockIdx.x * TT;
    const float* Hb = H + ((size_t)b * T_ + t0) * D_;
    const float* Ub = U + (size_t)b * J_ * D_;

    if (tid < J_) sm.uwbs[tid] = ws[WS_UWB + b * J_ + tid];

    float acc[4][8];
#pragma unroll
    for (int i = 0; i < 4; ++i)
#pragma unroll
        for (int j = 0; j < 8; ++j) acc[i][j] = 0.f;
    float hw[4] = {0.f, 0.f, 0.f, 0.f};

    // ---- GEMM1: S = Htile(64xD) @ (w3*U)^T(Dx128), K-chunked ----
    for (int d0 = 0; d0 < D_; d0 += KC) {
        __syncthreads();
#pragma unroll
        for (int q = 0; q < 2; ++q) {           // Ht: 512 float4
            int slot = tid + q * 256;
            int row = slot >> 3, dq = slot & 7;
            f4 v = *(const f4*)(Hb + (size_t)row * D_ + d0 + dq * 4);
            *(f4*)&sm.u.g1.Ht[row][dq * 4] = v;
        }
#pragma unroll
        for (int q = 0; q < 4; ++q) {           // Ut = U*w3: 1024 float4
            int slot = tid + q * 256;
            int row = slot >> 3, dq = slot & 7;
            f4 v = *(const f4*)(Ub + (size_t)row * D_ + d0 + dq * 4);
            f4 w3v = *(const f4*)(w + 2 * D_ + d0 + dq * 4);
            v.x *= w3v.x; v.y *= w3v.y; v.z *= w3v.z; v.w *= w3v.w;
            *(f4*)&sm.u.g1.Ut[row][dq * 4] = v;
        }
        if (tid < KC) sm.u.g1.w1s[tid] = w[d0 + tid];
        __syncthreads();
#pragma unroll
        for (int kk = 0; kk < KC; kk += 4) {
            f4 w4 = *(const f4*)&sm.u.g1.w1s[kk];
            f4 a4[4];
#pragma unroll
            for (int i = 0; i < 4; ++i) a4[i] = *(const f4*)&sm.u.g1.Ht[ty * 4 + i][kk];
            f4 u4[8];
#pragma unroll
            for (int j = 0; j < 8; ++j) u4[j] = *(const f4*)&sm.u.g1.Ut[tx + 16 * j][kk];
#pragma unroll
            for (int i = 0; i < 4; ++i) {
#pragma unroll
                for (int j = 0; j < 8; ++j) {
                    acc[i][j] = fmaf(a4[i].x, u4[j].x, acc[i][j]);
                    acc[i][j] = fmaf(a4[i].y, u4[j].y, acc[i][j]);
                    acc[i][j] = fmaf(a4[i].z, u4[j].z, acc[i][j]);
                    acc[i][j] = fmaf(a4[i].w, u4[j].w, acc[i][j]);
                }
                hw[i] = fmaf(a4[i].x, w4.x, hw[i]);
                hw[i] = fmaf(a4[i].y, w4.y, hw[i]);
                hw[i] = fmaf(a4[i].z, w4.z, hw[i]);
                hw[i] = fmaf(a4[i].w, w4.w, hw[i]);
            }
        }
    }
    __syncthreads();   // GEMM1 LDS dead; P will overwrite it

    // ---- softmax over j, write att1, stash row-max m into att2 slot ----
    float* att1o = out + OFF_ATT1 + ((size_t)(b * T_ + t0)) * J_;
    float* m_out = out + OFF_ATT2 + (size_t)b * T_ + t0;
#pragma unroll
    for (int i = 0; i < 4; ++i) {
        int r = ty * 4 + i;
        float mx = -1e30f;
        float sv[8];
#pragma unroll
        for (int j = 0; j < 8; ++j) {
            float s = acc[i][j] + hw[i] + sm.uwbs[tx + 16 * j];
            sv[j] = s;
            mx = fmaxf(mx, s);
        }
#pragma unroll
        for (int off = 1; off < 16; off <<= 1) mx = fmaxf(mx, __shfl_xor(mx, off, 64));
        float sum = 0.f;
#pragma unroll
        for (int j = 0; j < 8; ++j) { sv[j] = __expf(sv[j] - mx); sum += sv[j]; }
#pragma unroll
        for (int off = 1; off < 16; off <<= 1) sum += __shfl_xor(sum, off, 64);
        float inv = 1.0f / sum;
#pragma unroll
        for (int j = 0; j < 8; ++j) {
            float p = sv[j] * inv;
            int c = tx + 16 * j;
            att1o[(size_t)r * J_ + c] = p;
            sm.u.P[r][c] = p;
        }
        if (tx == 0) m_out[r] = mx;
    }
    __syncthreads();

    // ---- GEMM2: agg1 = P(64x128) @ U[b](128x1024), fused G chunk 0..2 ----
    float* Gb = out + OFF_G + ((size_t)(b * T_ + t0)) * 4096;
    for (int d0 = 0; d0 < D_; d0 += 128) {
        float a2[4][8];
#pragma unroll
        for (int i = 0; i < 4; ++i)
#pragma unroll
            for (int j = 0; j < 8; ++j) a2[i][j] = 0.f;
        const float* up = Ub + d0 + tx * 8;
        for (int kk = 0; kk < J_; kk += 4) {
            float pa[4][4];
#pragma unroll
            for (int i = 0; i < 4; ++i) {
                f4 t4 = *(const f4*)&sm.u.P[ty * 4 + i][kk];
                pa[i][0] = t4.x; pa[i][1] = t4.y; pa[i][2] = t4.z; pa[i][3] = t4.w;
            }
#pragma unroll
            for (int e = 0; e < 4; ++e) {
                f4 ua  = *(const f4*)up;
                f4 ubv = *(const f4*)(up + 4);
                up += D_;
#pragma unroll
                for (int i = 0; i < 4; ++i) {
                    float p = pa[i][e];
                    a2[i][0] = fmaf(p, ua.x,  a2[i][0]);
                    a2[i][1] = fmaf(p, ua.y,  a2[i][1]);
                    a2[i][2] = fmaf(p, ua.z,  a2[i][2]);
                    a2[i][3] = fmaf(p, ua.w,  a2[i][3]);
                    a2[i][4] = fmaf(p, ubv.x, a2[i][4]);
                    a2[i][5] = fmaf(p, ubv.y, a2[i][5]);
                    a2[i][6] = fmaf(p, ubv.z, a2[i][6]);
                    a2[i][7] = fmaf(p, ubv.w, a2[i][7]);
                }
            }
        }
#pragma unroll
        for (int i = 0; i < 4; ++i) {
            int r = ty * 4 + i;
            const float* hp = Hb + (size_t)r * D_ + d0 + tx * 8;
            f4 h0 = *(const f4*)hp;
            f4 h1 = *(const f4*)(hp + 4);
            float* g = Gb + (size_t)r * 4096 + d0 + tx * 8;
            f4 A0 = make_float4(a2[i][0], a2[i][1], a2[i][2], a2[i][3]);
            f4 A1 = make_float4(a2[i][4], a2[i][5], a2[i][6], a2[i][7]);
            *(f4*)(g)        = h0;
            *(f4*)(g + 4)    = h1;
            *(f4*)(g + 1024) = A0;
            *(f4*)(g + 1028) = A1;
            *(f4*)(g + 2048) = make_float4(h0.x * A0.x, h0.y * A0.y, h0.z * A0.z, h0.w * A0.w);
            *(f4*)(g + 2052) = make_float4(h1.x * A1.x, h1.y * A1.y, h1.z * A1.z, h1.w * A1.w);
        }
    }
}

// ---------------- K3: att2 = softmax_T(m) in-place in att2 slot ----------
__global__ __launch_bounds__(256) void k_att2(float* __restrict__ out) {
    int b = blockIdx.x, tid = threadIdx.x;
    float* mptr = out + OFF_ATT2 + (size_t)b * T_;
    float mv[8];
    float mx = -1e30f;
#pragma unroll
    for (int k = 0; k < 8; ++k) { mv[k] = mptr[tid + k * 256]; mx = fmaxf(mx, mv[k]); }
#pragma unroll
    for (int off = 1; off < 64; off <<= 1) mx = fmaxf(mx, __shfl_xor(mx, off, 64));
    __shared__ float redm[4], reds[4];
    if ((tid & 63) == 0) redm[tid >> 6] = mx;
    __syncthreads();
    float M = fmaxf(fmaxf(redm[0], redm[1]), fmaxf(redm[2], redm[3]));
    float s = 0.f;
#pragma unroll
    for (int k = 0; k < 8; ++k) { mv[k] = __expf(mv[k] - M); s += mv[k]; }
#pragma unroll
    for (int off = 1; off < 64; off <<= 1) s += __shfl_xor(s, off, 64);
    if ((tid & 63) == 0) reds[tid >> 6] = s;
    __syncthreads();
    float inv = 1.f / (reds[0] + reds[1] + reds[2] + reds[3]);
#pragma unroll
    for (int k = 0; k < 8; ++k) mptr[tid + k * 256] = mv[k] * inv;
}

// ---------------- K4: agg2[b,d] = sum_t att2[b,t] * H[b,t,d] -------------
__global__ __launch_bounds__(256) void k_agg2(const float* __restrict__ H,
                                              const float* __restrict__ att2,
                                              float* __restrict__ ws) {
    int b = blockIdx.y;
    int d0 = blockIdx.x * 64;
    int c = threadIdx.x & 63;
    int tq = threadIdx.x >> 6;
    const float* Hb = H + (size_t)b * T_ * D_;
    const float* a2 = att2 + (size_t)b * T_;
    float acc = 0.f;
#pragma unroll 8
    for (int t = tq; t < T_; t += 4)
        acc = fmaf(a2[t], Hb[(size_t)t * D_ + d0 + c], acc);
    __shared__ float red[4][64];
    red[tq][c] = acc;
    __syncthreads();
    if (tq == 0)
        ws[WS_AGG2 + b * D_ + d0 + c] = red[0][c] + red[1][c] + red[2][c] + red[3][c];
}

// ---------------- K5: G chunk3 = H * agg2 (broadcast over t) -------------
__global__ __launch_bounds__(256) void k_chunk3(const float* __restrict__ H,
                                                const float* __restrict__ ws,
                                                float* __restrict__ out) {
    size_t id = (size_t)blockIdx.x * 256 + threadIdx.x;  // float4 index
    int d4 = (int)(id & 255);
    int t  = (int)((id >> 8) & 2047);
    int b  = (int)(id >> 19);
    f4 h = *(const f4*)(H + id * 4);
    f4 a = *(const f4*)(ws + WS_AGG2 + b * D_ + d4 * 4);
    f4 r = make_float4(h.x * a.x, h.y * a.y, h.z * a.z, h.w * a.w);
    *(f4*)(out + OFF_G + ((size_t)(b * T_ + t)) * 4096 + 3072 + d4 * 4) = r;
}

extern "C" void kernel_launch(void* const* d_in, const int* in_sizes, int n_in,
                              void* d_out, int out_size, void* d_ws, size_t ws_size,
                              hipStream_t stream) {
    const float* H    = (const float*)d_in[0];
    const float* U    = (const float*)d_in[1];
    const float* w    = (const float*)d_in[2];
    const float* bias = (const float*)d_in[3];
    float* out = (float*)d_out;
    float* ws  = (float*)d_ws;

    k_uwb   <<<dim3(B_ * J_),      dim3(256), 0, stream>>>(U, w, bias, ws);
    k_main  <<<dim3(T_ / TT, B_),  dim3(256), 0, stream>>>(H, U, w, ws, out);
    k_att2  <<<dim3(B_),           dim3(256), 0, stream>>>(out);
    k_agg2  <<<dim3(D_ / 64, B_),  dim3(256), 0, stream>>>(H, out + OFF_ATT2, ws);
    k_chunk3<<<dim3((B_ * T_ * (D_ / 4)) / 256), dim3(256), 0, stream>>>(H, ws, out);
}